// Round 1
// baseline (105.512 us; speedup 1.0000x reference)
//
#include <hip/hip_runtime.h>
#include <math.h>

#define BATCH 8192
#define DIM   2048

// Table entry stride 13 floats: gcd(13,32)=1 -> random-idx LDS reads/writes
// spread over all 32 banks (~2 lanes/bank = free, m136). Entries hold 9
// floats (3x3), 4 pad. Table = 256 8-step-product entries + v[3] + pad.
#define TSTR 13
#define TBL_FLOATS (256 * TSTR + 4)   // 3332 floats = 833 float4 granules

// ---- cross-lane helpers -----------------------------------------------
// xor-pairing substitutes for shfl_down in the ordered reduction tree:
// every lane consumed at stage o has its low bits clear, so its partner
// i^o == i+o and computes R@S in the correct order. Other lanes hold
// garbage that is never consumed on lane 0's path.
__device__ __forceinline__ float sh_x1(float x) {
#if __has_builtin(__builtin_amdgcn_update_dpp)
    return __uint_as_float((unsigned)__builtin_amdgcn_update_dpp(
        0, (int)__float_as_uint(x), 0xB1, 0xF, 0xF, false)); // quad_perm [1,0,3,2]
#else
    return __shfl_xor(x, 1, 64);
#endif
}
__device__ __forceinline__ float sh_x2(float x) {
#if __has_builtin(__builtin_amdgcn_update_dpp)
    return __uint_as_float((unsigned)__builtin_amdgcn_update_dpp(
        0, (int)__float_as_uint(x), 0x4E, 0xF, 0xF, false)); // quad_perm [2,3,0,1]
#else
    return __shfl_xor(x, 2, 64);
#endif
}
__device__ __forceinline__ float sh_x4(float x) {
#if __has_builtin(__builtin_amdgcn_ds_swizzle)
    return __uint_as_float((unsigned)__builtin_amdgcn_ds_swizzle(
        (int)__float_as_uint(x), 0x101F));                   // xor 4
#else
    return __shfl_xor(x, 4, 64);
#endif
}
__device__ __forceinline__ float sh_x8(float x) {
#if __has_builtin(__builtin_amdgcn_ds_swizzle)
    return __uint_as_float((unsigned)__builtin_amdgcn_ds_swizzle(
        (int)__float_as_uint(x), 0x201F));                   // xor 8
#else
    return __shfl_xor(x, 8, 64);
#endif
}
__device__ __forceinline__ float sh_x16(float x) {
#if __has_builtin(__builtin_amdgcn_ds_swizzle)
    return __uint_as_float((unsigned)__builtin_amdgcn_ds_swizzle(
        (int)__float_as_uint(x), 0x401F));                   // xor 16
#else
    return __shfl_xor(x, 16, 64);
#endif
}
__device__ __forceinline__ float sh_d32(float x) {
#if __has_builtin(__builtin_amdgcn_permlane32_swap)
    auto r = __builtin_amdgcn_permlane32_swap(
        __float_as_uint(x), __float_as_uint(x), false, false);
    return __uint_as_float(r[1]);   // updated vsrc: lanes 0-31 = x[lane+32]
#else
    return __shfl_down(x, 32, 64);
#endif
}

#define RSTAGE(SHUF) do {                                                   \
    float S[9];                                                             \
    _Pragma("unroll")                                                       \
    for (int e = 0; e < 9; ++e) S[e] = SHUF(R[e]);                          \
    float osc = SHUF(lsc);                                                  \
    float nR[9];                                                            \
    _Pragma("unroll")                                                       \
    for (int i = 0; i < 3; ++i) {                                           \
        nR[i*3+0] = fmaf(R[i*3+0], S[0], fmaf(R[i*3+1], S[3], R[i*3+2]*S[6])); \
        nR[i*3+1] = fmaf(R[i*3+0], S[1], fmaf(R[i*3+1], S[4], R[i*3+2]*S[7])); \
        nR[i*3+2] = fmaf(R[i*3+0], S[2], fmaf(R[i*3+1], S[5], R[i*3+2]*S[8])); \
    }                                                                       \
    _Pragma("unroll")                                                       \
    for (int e = 0; e < 9; ++e) R[e] = nR[e];                               \
    lsc += osc;                                                             \
} while (0)

// ---- prep: build the (block-invariant!) 8-step table ONCE --------------
// Previously every one of 2048 blocks rebuilt the identical 13 KB table
// (params + expf + t4 chain + 256 matmuls + conflicted LDS writes).
__global__ void hmm_prep(const float* __restrict__ tp,
                         const float* __restrict__ ep,
                         const float* __restrict__ sp,
                         float* __restrict__ tbl)
{
    __shared__ float t4s[16 * TSTR];
    const int tid = threadIdx.x;

    float T[3][3], E[3][2], pi[3];
    #pragma unroll
    for (int i = 0; i < 3; ++i) {
        float a0 = tp[i*3+0], a1 = tp[i*3+1], a2 = tp[i*3+2];
        float mx = fmaxf(a0, fmaxf(a1, a2));
        float e0 = __expf(a0-mx), e1 = __expf(a1-mx), e2 = __expf(a2-mx);
        float inv = 1.0f / (e0+e1+e2);
        T[i][0] = e0*inv; T[i][1] = e1*inv; T[i][2] = e2*inv;
    }
    #pragma unroll
    for (int s = 0; s < 3; ++s) {
        float a0 = ep[s*2+0], a1 = ep[s*2+1];
        float mx = fmaxf(a0, a1);
        float e0 = __expf(a0-mx), e1 = __expf(a1-mx);
        float inv = 1.0f / (e0+e1);
        E[s][0] = e0*inv; E[s][1] = e1*inv;
    }
    {
        float a0 = sp[0], a1 = sp[1], a2 = sp[2];
        float mx = fmaxf(a0, fmaxf(a1, a2));
        float e0 = __expf(a0-mx), e1 = __expf(a1-mx), e2 = __expf(a2-mx);
        float inv = 1.0f / (e0+e1+e2);
        pi[0] = e0*inv; pi[1] = e1*inv; pi[2] = e2*inv;
    }

    if (tid == 0) {   // solve T^T v = pi (Cramer); row-independent
        float c00 =  (T[1][1]*T[2][2] - T[1][2]*T[2][1]);
        float c01 = -(T[1][0]*T[2][2] - T[1][2]*T[2][0]);
        float c02 =  (T[1][0]*T[2][1] - T[1][1]*T[2][0]);
        float c10 = -(T[0][1]*T[2][2] - T[0][2]*T[2][1]);
        float c11 =  (T[0][0]*T[2][2] - T[0][2]*T[2][0]);
        float c12 = -(T[0][0]*T[2][1] - T[0][1]*T[2][0]);
        float c20 =  (T[0][1]*T[1][2] - T[0][2]*T[1][1]);
        float c21 = -(T[0][0]*T[1][2] - T[0][2]*T[1][0]);
        float c22 =  (T[0][0]*T[1][1] - T[0][1]*T[1][0]);
        float det = T[0][0]*c00 + T[0][1]*c01 + T[0][2]*c02;
        float invd = 1.0f / det;
        tbl[256*TSTR + 0] = (pi[0]*c00 + pi[1]*c01 + pi[2]*c02) * invd;
        tbl[256*TSTR + 1] = (pi[0]*c10 + pi[1]*c11 + pi[2]*c12) * invd;
        tbl[256*TSTR + 2] = (pi[0]*c20 + pi[1]*c21 + pi[2]*c22) * invd;
        tbl[256*TSTR + 3] = 0.0f;   // keep the float4 copy tail defined
    }

    if (tid < 16) {   // 4-step table (same math/order as before)
        float M0[9], M1[9];
        #pragma unroll
        for (int k = 0; k < 3; ++k)
            #pragma unroll
            for (int j = 0; j < 3; ++j) {
                M0[k*3+j] = T[k][j] * E[j][0];
                M1[k*3+j] = T[k][j] * E[j][1];
            }
        int code = tid;
        float A[9];
        const float* F0 = (code & 1) ? M1 : M0;
        #pragma unroll
        for (int e = 0; e < 9; ++e) A[e] = F0[e];
        code >>= 1;
        #pragma unroll
        for (int s = 1; s < 4; ++s) {
            const float* F = (code & 1) ? M1 : M0;
            code >>= 1;
            float Z[9];
            #pragma unroll
            for (int i = 0; i < 3; ++i)
                #pragma unroll
                for (int j = 0; j < 3; ++j)
                    Z[i*3+j] = fmaf(A[i*3+0], F[0*3+j],
                               fmaf(A[i*3+1], F[1*3+j], A[i*3+2]*F[2*3+j]));
            #pragma unroll
            for (int e = 0; e < 9; ++e) A[e] = Z[e];
        }
        #pragma unroll
        for (int e = 0; e < 9; ++e) t4s[tid*TSTR + e] = A[e];
    }
    __syncthreads();

    // t8[c] = t4[c&15] . t4[c>>4]  (one entry per thread)
    const float* A  = &t4s[(tid & 15) * TSTR];
    const float* Bm = &t4s[(tid >> 4) * TSTR];
    float Z[9];
    #pragma unroll
    for (int i = 0; i < 3; ++i)
        #pragma unroll
        for (int j = 0; j < 3; ++j)
            Z[i*3+j] = fmaf(A[i*3+0], Bm[0*3+j],
                       fmaf(A[i*3+1], Bm[1*3+j], A[i*3+2]*Bm[2*3+j]));
    #pragma unroll
    for (int e = 0; e < 9; ++e) tbl[tid*TSTR + e] = Z[e];
}

// ---- main: one wave per batch row --------------------------------------
__global__ __launch_bounds__(256, 6)
void hmm_fwd(const int* __restrict__ y,
             const float* __restrict__ tbl,
             float* __restrict__ row_lp)
{
    __shared__ __align__(16) float t8s[TBL_FLOATS];
    __shared__ __align__(16) unsigned char ystage[4][512];

    const int tid  = threadIdx.x;
    const int lane = tid & 63;
    const int wid  = tid >> 6;
    const int b    = blockIdx.x * 4 + wid;

    // coalesced y load -> 4-bit pack -> byte stage (unchanged)
    {
        const int* __restrict__ p = y + (size_t)b * DIM + lane * 4;
        unsigned char* __restrict__ row = ystage[wid];
        #pragma unroll
        for (int g = 0; g < 8; ++g) {
            int4 v = *reinterpret_cast<const int4*>(p + g * 256);
            row[64*g + lane] =
                (unsigned char)(v.x | (v.y<<1) | (v.z<<2) | (v.w<<3));
        }
    }

    // 13 KB table: global (L2/L3-hot) -> LDS, 833 float4 granules
    {
        const float4* __restrict__ src = reinterpret_cast<const float4*>(tbl);
        float4* __restrict__ dst = reinterpret_cast<float4*>(t8s);
        #pragma unroll
        for (int g = 0; g < 4; ++g) {
            int i = tid + g * 256;
            if (i < TBL_FLOATS / 4) dst[i] = src[i];
        }
    }
    __syncthreads();   // covers ystage AND t8s (single barrier now)

    // per-lane chunk: 4 groups of 8 steps, codes from one b64 read
    uint2 q = *reinterpret_cast<const uint2*>(&ystage[wid][8 * lane]);

    float R[9] = {1.f,0.f,0.f, 0.f,1.f,0.f, 0.f,0.f,1.f};
    float lsc = 0.0f;

    #pragma unroll
    for (int j = 0; j < 4; ++j) {
        unsigned w  = (j < 2) ? q.x : q.y;
        unsigned sh = (j & 1) * 16;
        int idx = (int)(((w >> sh) & 15u) | ((w >> (sh + 4)) & 0xF0u));
        const float* gp = &t8s[idx * TSTR];   // stride-13: conflict-free
        float g0 = gp[0], g1 = gp[1], g2 = gp[2],
              g3 = gp[3], g4 = gp[4], g5 = gp[5],
              g6 = gp[6], g7 = gp[7], g8 = gp[8];
        float nR[9];
        #pragma unroll
        for (int i = 0; i < 3; ++i) {
            nR[i*3+0] = fmaf(R[i*3+0], g0, fmaf(R[i*3+1], g3, R[i*3+2]*g6));
            nR[i*3+1] = fmaf(R[i*3+0], g1, fmaf(R[i*3+1], g4, R[i*3+2]*g7));
            nR[i*3+2] = fmaf(R[i*3+0], g2, fmaf(R[i*3+1], g5, R[i*3+2]*g8));
        }
        #pragma unroll
        for (int e = 0; e < 9; ++e) R[e] = nR[e];

        if (j == 1 || j == 3) {
            float m = R[0];
            #pragma unroll
            for (int e = 1; e < 9; ++e) m = fmaxf(m, R[e]);
            lsc += __logf(m);
            float inv = 1.0f / m;
            #pragma unroll
            for (int e = 0; e < 9; ++e) R[e] *= inv;
        }
    }

    // ordered wave reduction, now off the bpermute path:
    // DPP (o=1,2) + ds_swizzle (o=4,8,16) + permlane32_swap (o=32)
    RSTAGE(sh_x1);
    RSTAGE(sh_x2);
    RSTAGE(sh_x4);
    RSTAGE(sh_x8);
    RSTAGE(sh_x16);
    RSTAGE(sh_d32);

    if (lane == 0) {
        float r0 = R[0] + R[1] + R[2];
        float r1 = R[3] + R[4] + R[5];
        float r2 = R[6] + R[7] + R[8];
        const float* v = &t8s[256 * TSTR];
        float p = fmaf(v[0], r0, fmaf(v[1], r1, v[2] * r2));
        row_lp[b] = __logf(p) + lsc;
    }
}

__global__ void reduce_mean(const float* __restrict__ row, float* __restrict__ out)
{
    float s = 0.0f;
    for (int i = threadIdx.x; i < BATCH; i += 1024) s += row[i];
    #pragma unroll
    for (int o = 32; o > 0; o >>= 1) s += __shfl_down(s, o, 64);
    __shared__ float sm[16];
    int w = threadIdx.x >> 6;
    if ((threadIdx.x & 63) == 0) sm[w] = s;
    __syncthreads();
    if (threadIdx.x == 0) {
        float t = 0.0f;
        #pragma unroll
        for (int i = 0; i < 16; ++i) t += sm[i];
        out[0] = t * (1.0f / BATCH);
    }
}

extern "C" void kernel_launch(void* const* d_in, const int* in_sizes, int n_in,
                              void* d_out, int out_size, void* d_ws, size_t ws_size,
                              hipStream_t stream)
{
    const int*   y  = (const int*)d_in[0];
    const float* tp = (const float*)d_in[1];
    const float* ep = (const float*)d_in[2];
    const float* sp = (const float*)d_in[3];
    float* out = (float*)d_out;
    float* row = (float*)d_ws;                 // 32 KB: per-row log-probs
    float* tbl = (float*)d_ws + BATCH;         // 13.3 KB: 8-step table + v

    hmm_prep<<<1, 256, 0, stream>>>(tp, ep, sp, tbl);
    hmm_fwd<<<BATCH/4, 256, 0, stream>>>(y, tbl, row);
    reduce_mean<<<1, 1024, 0, stream>>>(row, out);
}

// Round 2
// 101.313 us; speedup vs baseline: 1.0414x; 1.0414x over previous
//
#include <hip/hip_runtime.h>
#include <math.h>

#define BATCH 8192
#define DIM   2048

// Table entry stride 13 floats: gcd(13,32)=1 -> random-idx LDS reads and
// the t8 build writes spread over all 32 banks (~2 lanes/bank = free, m136).
#define TSTR 13

// ---- cross-lane helpers -----------------------------------------------
// xor-pairing substitutes for shfl_down in the ordered reduction tree:
// every lane consumed at stage o has its low bits clear, so its partner
// i^o == i+o and computes R@S in the correct order. Lanes whose value
// becomes garbage are never consumed on lane 0's path.
__device__ __forceinline__ float sh_x1(float x) {
#if __has_builtin(__builtin_amdgcn_update_dpp)
    return __uint_as_float((unsigned)__builtin_amdgcn_update_dpp(
        0, (int)__float_as_uint(x), 0xB1, 0xF, 0xF, false)); // quad_perm [1,0,3,2]
#else
    return __shfl_xor(x, 1, 64);
#endif
}
__device__ __forceinline__ float sh_x2(float x) {
#if __has_builtin(__builtin_amdgcn_update_dpp)
    return __uint_as_float((unsigned)__builtin_amdgcn_update_dpp(
        0, (int)__float_as_uint(x), 0x4E, 0xF, 0xF, false)); // quad_perm [2,3,0,1]
#else
    return __shfl_xor(x, 2, 64);
#endif
}
__device__ __forceinline__ float sh_x4(float x) {
#if __has_builtin(__builtin_amdgcn_ds_swizzle)
    return __uint_as_float((unsigned)__builtin_amdgcn_ds_swizzle(
        (int)__float_as_uint(x), 0x101F));                   // xor 4
#else
    return __shfl_xor(x, 4, 64);
#endif
}
__device__ __forceinline__ float sh_x8(float x) {
#if __has_builtin(__builtin_amdgcn_ds_swizzle)
    return __uint_as_float((unsigned)__builtin_amdgcn_ds_swizzle(
        (int)__float_as_uint(x), 0x201F));                   // xor 8
#else
    return __shfl_xor(x, 8, 64);
#endif
}
__device__ __forceinline__ float sh_x16(float x) {
#if __has_builtin(__builtin_amdgcn_ds_swizzle)
    return __uint_as_float((unsigned)__builtin_amdgcn_ds_swizzle(
        (int)__float_as_uint(x), 0x401F));                   // xor 16
#else
    return __shfl_xor(x, 16, 64);
#endif
}
__device__ __forceinline__ float sh_d32(float x) {
#if __has_builtin(__builtin_amdgcn_permlane32_swap)
    auto r = __builtin_amdgcn_permlane32_swap(
        __float_as_uint(x), __float_as_uint(x), false, false);
    return __uint_as_float(r[1]);   // updated vsrc: lanes 0-31 = x[lane+32]
#else
    return __shfl_down(x, 32, 64);
#endif
}

#define RSTAGE(SHUF) do {                                                   \
    float S[9];                                                             \
    _Pragma("unroll")                                                       \
    for (int e = 0; e < 9; ++e) S[e] = SHUF(R[e]);                          \
    float osc = SHUF(lsc);                                                  \
    float nR[9];                                                            \
    _Pragma("unroll")                                                       \
    for (int i = 0; i < 3; ++i) {                                           \
        nR[i*3+0] = fmaf(R[i*3+0], S[0], fmaf(R[i*3+1], S[3], R[i*3+2]*S[6])); \
        nR[i*3+1] = fmaf(R[i*3+0], S[1], fmaf(R[i*3+1], S[4], R[i*3+2]*S[7])); \
        nR[i*3+2] = fmaf(R[i*3+0], S[2], fmaf(R[i*3+1], S[5], R[i*3+2]*S[8])); \
    }                                                                       \
    _Pragma("unroll")                                                       \
    for (int e = 0; e < 9; ++e) R[e] = nR[e];                               \
    lsc += osc;                                                             \
} while (0)

// One wave per batch row; fused table build (R1 post-mortem: per-block build
// is measured-free, while a separate serial prep launch cost +4us in the
// graph). Stride-13 tables + DPP/swizzle reduction kept from R1.
__global__ __launch_bounds__(256, 6)
void hmm_fwd(const int* __restrict__ y,
             const float* __restrict__ tp,
             const float* __restrict__ ep,
             const float* __restrict__ sp,
             float* __restrict__ row_lp)
{
    __shared__ __align__(16) float t4[16 * TSTR];
    __shared__ __align__(16) float t8[256 * TSTR];
    __shared__ __align__(16) unsigned char ystage[4][512];
    __shared__ float vlds[3];

    const int tid  = threadIdx.x;
    const int lane = tid & 63;
    const int wid  = tid >> 6;
    const int b    = blockIdx.x * 4 + wid;

    // ---- coalesced load -> pack -> byte store (all threads) ----
    {
        const int* __restrict__ p = y + (size_t)b * DIM + lane * 4;
        unsigned char* __restrict__ row = ystage[wid];
        #pragma unroll
        for (int g = 0; g < 8; ++g) {
            int4 v = *reinterpret_cast<const int4*>(p + g * 256);
            row[64*g + lane] =
                (unsigned char)(v.x | (v.y<<1) | (v.z<<2) | (v.w<<3));
        }
    }

    // ---- wave 0 only: params, v-solve, 4-step table ----
    if (wid == 0) {
        float T[3][3], E[3][2], pi[3];
        #pragma unroll
        for (int i = 0; i < 3; ++i) {
            float a0 = tp[i*3+0], a1 = tp[i*3+1], a2 = tp[i*3+2];
            float mx = fmaxf(a0, fmaxf(a1, a2));
            float e0 = __expf(a0-mx), e1 = __expf(a1-mx), e2 = __expf(a2-mx);
            float inv = 1.0f / (e0+e1+e2);
            T[i][0] = e0*inv; T[i][1] = e1*inv; T[i][2] = e2*inv;
        }
        #pragma unroll
        for (int s = 0; s < 3; ++s) {
            float a0 = ep[s*2+0], a1 = ep[s*2+1];
            float mx = fmaxf(a0, a1);
            float e0 = __expf(a0-mx), e1 = __expf(a1-mx);
            float inv = 1.0f / (e0+e1);
            E[s][0] = e0*inv; E[s][1] = e1*inv;
        }
        {
            float a0 = sp[0], a1 = sp[1], a2 = sp[2];
            float mx = fmaxf(a0, fmaxf(a1, a2));
            float e0 = __expf(a0-mx), e1 = __expf(a1-mx), e2 = __expf(a2-mx);
            float inv = 1.0f / (e0+e1+e2);
            pi[0] = e0*inv; pi[1] = e1*inv; pi[2] = e2*inv;
        }

        if (lane == 0) {   // v solves T^T v = pi; row-independent
            float c00 =  (T[1][1]*T[2][2] - T[1][2]*T[2][1]);
            float c01 = -(T[1][0]*T[2][2] - T[1][2]*T[2][0]);
            float c02 =  (T[1][0]*T[2][1] - T[1][1]*T[2][0]);
            float c10 = -(T[0][1]*T[2][2] - T[0][2]*T[2][1]);
            float c11 =  (T[0][0]*T[2][2] - T[0][2]*T[2][0]);
            float c12 = -(T[0][0]*T[2][1] - T[0][1]*T[2][0]);
            float c20 =  (T[0][1]*T[1][2] - T[0][2]*T[1][1]);
            float c21 = -(T[0][0]*T[1][2] - T[0][2]*T[1][0]);
            float c22 =  (T[0][0]*T[1][1] - T[0][1]*T[1][0]);
            float det = T[0][0]*c00 + T[0][1]*c01 + T[0][2]*c02;
            float invd = 1.0f / det;
            vlds[0] = (pi[0]*c00 + pi[1]*c01 + pi[2]*c02) * invd;
            vlds[1] = (pi[0]*c10 + pi[1]*c11 + pi[2]*c12) * invd;
            vlds[2] = (pi[0]*c20 + pi[1]*c21 + pi[2]*c22) * invd;
        }

        // per-step matrices M_y[k*3+j] = T[k][j] * E[j][y]
        float M0[9], M1[9];
        #pragma unroll
        for (int k = 0; k < 3; ++k)
            #pragma unroll
            for (int j = 0; j < 3; ++j) {
                M0[k*3+j] = T[k][j] * E[j][0];
                M1[k*3+j] = T[k][j] * E[j][1];
            }

        if (lane < 16) {   // 4-step table
            int code = lane;
            float A[9];
            const float* F0 = (code & 1) ? M1 : M0;
            #pragma unroll
            for (int e = 0; e < 9; ++e) A[e] = F0[e];
            code >>= 1;
            #pragma unroll
            for (int s = 1; s < 4; ++s) {
                const float* F = (code & 1) ? M1 : M0;
                code >>= 1;
                float Z[9];
                #pragma unroll
                for (int i = 0; i < 3; ++i)
                    #pragma unroll
                    for (int j = 0; j < 3; ++j)
                        Z[i*3+j] = fmaf(A[i*3+0], F[0*3+j],
                                   fmaf(A[i*3+1], F[1*3+j], A[i*3+2]*F[2*3+j]));
                #pragma unroll
                for (int e = 0; e < 9; ++e) A[e] = Z[e];
            }
            #pragma unroll
            for (int e = 0; e < 9; ++e) t4[lane*TSTR + e] = A[e];
        }
    }
    __syncthreads();   // covers t4, vlds AND ystage

    // ---- 8-step table: t8[c] = t4[c&15] . t4[c>>4] (all 256 threads) ----
    {
        const float* A  = &t4[(tid & 15) * TSTR];   // stride-13: scalar reads,
        const float* Bm = &t4[(tid >> 4) * TSTR];   // conflict-free banks
        float Z[9];
        #pragma unroll
        for (int i = 0; i < 3; ++i)
            #pragma unroll
            for (int j = 0; j < 3; ++j)
                Z[i*3+j] = fmaf(A[i*3+0], Bm[0*3+j],
                           fmaf(A[i*3+1], Bm[1*3+j], A[i*3+2]*Bm[2*3+j]));
        #pragma unroll
        for (int e = 0; e < 9; ++e) t8[tid*TSTR + e] = Z[e];
    }
    __syncthreads();

    // ---- per-lane chunk: 4 groups of 8 steps, codes from one b64 read ----
    uint2 q = *reinterpret_cast<const uint2*>(&ystage[wid][8 * lane]);

    float R[9] = {1.f,0.f,0.f, 0.f,1.f,0.f, 0.f,0.f,1.f};
    float lsc = 0.0f;

    #pragma unroll
    for (int j = 0; j < 4; ++j) {
        unsigned w  = (j < 2) ? q.x : q.y;
        unsigned sh = (j & 1) * 16;
        int idx = (int)(((w >> sh) & 15u) | ((w >> (sh + 4)) & 0xF0u));
        const float* gp = &t8[idx * TSTR];   // stride-13: conflict-free
        float g0 = gp[0], g1 = gp[1], g2 = gp[2],
              g3 = gp[3], g4 = gp[4], g5 = gp[5],
              g6 = gp[6], g7 = gp[7], g8 = gp[8];
        float nR[9];
        #pragma unroll
        for (int i = 0; i < 3; ++i) {
            nR[i*3+0] = fmaf(R[i*3+0], g0, fmaf(R[i*3+1], g3, R[i*3+2]*g6));
            nR[i*3+1] = fmaf(R[i*3+0], g1, fmaf(R[i*3+1], g4, R[i*3+2]*g7));
            nR[i*3+2] = fmaf(R[i*3+0], g2, fmaf(R[i*3+1], g5, R[i*3+2]*g8));
        }
        #pragma unroll
        for (int e = 0; e < 9; ++e) R[e] = nR[e];

        if (j == 1 || j == 3) {
            float m = R[0];
            #pragma unroll
            for (int e = 1; e < 9; ++e) m = fmaxf(m, R[e]);
            lsc += __logf(m);
            float inv = 1.0f / m;
            #pragma unroll
            for (int e = 0; e < 9; ++e) R[e] *= inv;
        }
    }

    // ---- ordered wave reduction: DPP + ds_swizzle + permlane32_swap ----
    RSTAGE(sh_x1);
    RSTAGE(sh_x2);
    RSTAGE(sh_x4);
    RSTAGE(sh_x8);
    RSTAGE(sh_x16);
    RSTAGE(sh_d32);

    // ---- lane 0: row log-prob to workspace ----
    if (lane == 0) {
        float r0 = R[0] + R[1] + R[2];
        float r1 = R[3] + R[4] + R[5];
        float r2 = R[6] + R[7] + R[8];
        float p  = fmaf(vlds[0], r0, fmaf(vlds[1], r1, vlds[2] * r2));
        row_lp[b] = __logf(p) + lsc;
    }
}

__global__ void reduce_mean(const float* __restrict__ row, float* __restrict__ out)
{
    float s = 0.0f;
    for (int i = threadIdx.x; i < BATCH; i += 1024) s += row[i];
    #pragma unroll
    for (int o = 32; o > 0; o >>= 1) s += __shfl_down(s, o, 64);
    __shared__ float sm[16];
    int w = threadIdx.x >> 6;
    if ((threadIdx.x & 63) == 0) sm[w] = s;
    __syncthreads();
    if (threadIdx.x == 0) {
        float t = 0.0f;
        #pragma unroll
        for (int i = 0; i < 16; ++i) t += sm[i];
        out[0] = t * (1.0f / BATCH);
    }
}

extern "C" void kernel_launch(void* const* d_in, const int* in_sizes, int n_in,
                              void* d_out, int out_size, void* d_ws, size_t ws_size,
                              hipStream_t stream)
{
    const int*   y  = (const int*)d_in[0];
    const float* tp = (const float*)d_in[1];
    const float* ep = (const float*)d_in[2];
    const float* sp = (const float*)d_in[3];
    float* out = (float*)d_out;
    float* row = (float*)d_ws;   // 32 KB of the workspace

    hmm_fwd<<<BATCH/4, 256, 0, stream>>>(y, tp, ep, sp, row);
    reduce_mean<<<1, 1024, 0, stream>>>(row, out);
}